// Round 22
// baseline (49.851 us; speedup 1.0000x reference)
//
#include <hip/hip_runtime.h>

#define NB   64
#define LSEQ 8192
#define NW   8190
#define HD   90
#define AMPF 28.5f

typedef _Float16 half8  __attribute__((ext_vector_type(8)));
typedef float    f32x16 __attribute__((ext_vector_type(16)));
typedef __fp16   fp16x2 __attribute__((ext_vector_type(2)));

union FragU { uint4 u; half8 h; };

__device__ __forceinline__ unsigned pk2(float a, float b) {
  fp16x2 v = __builtin_amdgcn_cvt_pkrtz(a, b);
  return __builtin_bit_cast(unsigned, v);
}
__device__ __forceinline__ unsigned pkmax0(unsigned w) {
  unsigned r;
  asm("v_pk_max_f16 %0, %1, %2" : "=v"(r) : "v"(w), "v"(0u));
  return r;
}
__device__ __forceinline__ int imin(int a, int b) { return a < b ? a : b; }

// ============================================================================
// 32x32x16 swapped formulation with CUSTOM symmetric K-slot map.
// D[n][w] = sum_k W[k][n] * H[k][w]. A = weights (n = 32*t2 + (lane&31)),
// B = activations (w = lane&31, same lane as C cols). Slot map (A and B agree;
// HW slot->k permutation cancels):  k = 16s + 4g + (i&3) + 8*(i>>2), g=lane>>5.
// C layout (verified m74/m101): lane holds col w=lane&31, reg r -> row
// n = (r&3) + 8*(r>>2) + 4g.  With this map, next-layer B-frag for step
// s' = 2*t2 + h is simply:
//   word m (m=0..3) = pk2(acc[t2][8h+2m], acc[t2][8h+2m+1])   -- pure packing,
// zero cross-lane ops (the 32x32 analog of R18's verified 16x16 trick).
// Layer-1 (kin=8): step s=0 slots k<8 hold z=[c0,c1,x0,x1,x2,c2,c3,1]:
//   g=0 -> k 0..3 = z[0..3] in slots i=0..3; g=1 -> k 4..7 = z[4..7] in i=0..3.
// Bias-propagation: row n==90 gets A[k==kin][90]=1 so it outputs 1.0 every
// layer and serves as the next layer's k=90 bias activation.
// frag ids: 0..2 layer1 (t2=f) | 3..74 hidden (f=3+L*18+t2*6+s) | 75..80 l6.
// ============================================================================
__global__ void dnpu_pack(const float* __restrict__ W1, const float* __restrict__ b1,
                          const float* __restrict__ W2, const float* __restrict__ b2,
                          const float* __restrict__ W3, const float* __restrict__ b3,
                          const float* __restrict__ W4, const float* __restrict__ b4,
                          const float* __restrict__ W5, const float* __restrict__ b5,
                          const float* __restrict__ W6, const float* __restrict__ b6,
                          uint4* __restrict__ frags) {
  int tid = blockIdx.x * blockDim.x + threadIdx.x;
  if (tid >= 81 * 64) return;
  int f = tid >> 6, lane = tid & 63;
  int c = lane & 31, g = lane >> 5;
  FragU u;
  if (f < 3) {                       // layer 1, t2 = f, single k-step (kin=8)
    int n = 32 * f + c;
#pragma unroll
    for (int i = 0; i < 8; ++i) {
      int k = 4 * g + (i & 3) + 8 * (i >> 2);
      float val = 0.f;
      if (n < HD)      { if (k < 7) val = W1[k * HD + n]; else if (k == 7) val = b1[n]; }
      else if (n == HD && k == 7) val = 1.0f;             // bias-propagation
      u.h[i] = (_Float16)val;
    }
  } else if (f < 75) {
    int q = f - 3, L = q / 18, r = q % 18, t2 = r / 6, s = r % 6;
    const float* W    = (L == 0) ? W2 : (L == 1) ? W3 : (L == 2) ? W4 : W5;
    const float* bias = (L == 0) ? b2 : (L == 1) ? b3 : (L == 2) ? b4 : b5;
    int n = 32 * t2 + c;
#pragma unroll
    for (int i = 0; i < 8; ++i) {
      int k = 16 * s + 4 * g + (i & 3) + 8 * (i >> 2);     // custom map
      float val = 0.f;
      if (n < HD)      { if (k < HD) val = W[k * HD + n]; else if (k == HD) val = bias[n]; }
      else if (n == HD && k == HD) val = 1.0f;             // bias-propagation
      u.h[i] = (_Float16)val;
    }
  } else {                           // layer 6: t2=0, only row n==0 real
    int s = f - 75;
    int n = c;
#pragma unroll
    for (int i = 0; i < 8; ++i) {
      int k = 16 * s + 4 * g + (i & 3) + 8 * (i >> 2);
      float val = 0.f;
      if (n == 0) { if (k < HD) val = W6[k]; else if (k == HD) val = b6[0]; }
      u.h[i] = (_Float16)val;
    }
  }
  frags[f * 64 + lane] = u.u;
}

// acc (one t2-block) -> two next-layer B-frags (steps 2*t2 and 2*t2+1):
// pure packing, zero cross-lane ops.
__device__ __forceinline__ void pack_t2(const f32x16& a, uint4& b0, uint4& b1) {
  b0 = make_uint4(pkmax0(pk2(a[0],  a[1])),  pkmax0(pk2(a[2],  a[3])),
                  pkmax0(pk2(a[4],  a[5])),  pkmax0(pk2(a[6],  a[7])));
  b1 = make_uint4(pkmax0(pk2(a[8],  a[9])),  pkmax0(pk2(a[10], a[11])),
                  pkmax0(pk2(a[12], a[13])), pkmax0(pk2(a[14], a[15])));
}

// one hidden 96x96 layer (one 32-window tile); frags streamed from LDS.
__device__ __forceinline__ void hidden(const uint4* __restrict__ wfr, int lane,
                                       uint4 (&B)[6], const f32x16& zz) {
  uint4 Bn[6];
#pragma unroll
  for (int t2 = 0; t2 < 3; ++t2) {
    FragU Af0; Af0.u = wfr[(t2 * 6 + 0) * 64 + lane];
    f32x16 a = __builtin_amdgcn_mfma_f32_32x32x16_f16(
                 Af0.h, __builtin_bit_cast(half8, B[0]), zz, 0, 0, 0);
#pragma unroll
    for (int s = 1; s < 6; ++s) {
      FragU Af; Af.u = wfr[(t2 * 6 + s) * 64 + lane];
      a = __builtin_amdgcn_mfma_f32_32x32x16_f16(
            Af.h, __builtin_bit_cast(half8, B[s]), a, 0, 0, 0);
    }
    pack_t2(a, Bn[2 * t2], Bn[2 * t2 + 1]);
  }
#pragma unroll
  for (int i = 0; i < 6; ++i) B[i] = Bn[i];
}

// ---------------- main kernel ----------------
// R22: 32x32 shape (−12% MFMA issue cycles vs 16x16: 969 vs 844 FLOP/cyc/SIMD)
// + custom slot map => pack-only transition (no permlane), + R18's VERIFIED
// per-layer restage sync (free-run structure failed twice: R19 NaN, R21 23.1).
// Issue-port model: duration = MFMA + VALU + LDS issue cycles summed.
__global__ __launch_bounds__(256, 2)
void dnpu_mfma(const float* __restrict__ x, const float* __restrict__ cv,
               const uint4* __restrict__ frags, float* __restrict__ out) {
  __shared__ uint4 wfr[18 * 64];             // one layer's frags, 18,432 B
  const int tid  = threadIdx.x;
  const int lane = tid & 63, wid = tid >> 6;
  const int g = lane >> 5, c = lane & 31;
  const int b = blockIdx.y;

  f32x16 zz = (f32x16)(0.f);
  asm volatile("" : "+v"(zz));               // opaque zero C-operand

  // stage layer-2 frags
  for (int i = tid; i < 18 * 64; i += 256) wfr[i] = frags[3 * 64 + i];

  const float c0 = cv[0], c1 = cv[1], c2 = cv[2], c3 = cv[3];
  const float* xr = x + (size_t)b * LSEQ;
  const int rowbase = blockIdx.x * 128 + wid * 32;   // 1 tile x 32 windows/wave

  uint4 B[6];

  // ---- layer 1 -> B ----
  {
    const int w  = rowbase + c;
    const int xi = imin(w, LSEQ - 3);
    const float x0 = xr[xi], x1 = xr[xi + 1], x2 = xr[xi + 2];
    uint4 B1u;
    if (g == 0) B1u = make_uint4(pk2(c0, c1), pk2(x0, x1), 0u, 0u);
    else        B1u = make_uint4(pk2(x2, c2), pk2(c3, 1.0f), 0u, 0u);
#pragma unroll
    for (int t2 = 0; t2 < 3; ++t2) {
      FragU Af; Af.u = frags[t2 * 64 + lane];
      f32x16 a = __builtin_amdgcn_mfma_f32_32x32x16_f16(
                   Af.h, __builtin_bit_cast(half8, B1u), zz, 0, 0, 0);
      pack_t2(a, B[2 * t2], B[2 * t2 + 1]);
    }
  }

  __syncthreads();                                        // L2 frags ready
  hidden(wfr, lane, B, zz);                               // L2
  __syncthreads();
  for (int i = tid; i < 18 * 64; i += 256) wfr[i] = frags[(3 + 18) * 64 + i];
  __syncthreads();
  hidden(wfr, lane, B, zz);                               // L3
  __syncthreads();
  for (int i = tid; i < 18 * 64; i += 256) wfr[i] = frags[(3 + 36) * 64 + i];
  __syncthreads();
  hidden(wfr, lane, B, zz);                               // L4
  __syncthreads();
  for (int i = tid; i < 18 * 64; i += 256) wfr[i] = frags[(3 + 54) * 64 + i];
  __syncthreads();
  hidden(wfr, lane, B, zz);                               // L5

  // ---- layer 6: 96 -> 1 (row 0 = reg 0 of g==0 lanes), then * AMP ----
  {
    FragU A60; A60.u = frags[75 * 64 + lane];
    f32x16 a = __builtin_amdgcn_mfma_f32_32x32x16_f16(
                 A60.h, __builtin_bit_cast(half8, B[0]), zz, 0, 0, 0);
#pragma unroll
    for (int s = 1; s < 6; ++s) {
      FragU Af; Af.u = frags[(75 + s) * 64 + lane];
      a = __builtin_amdgcn_mfma_f32_32x32x16_f16(
            Af.h, __builtin_bit_cast(half8, B[s]), a, 0, 0, 0);
    }
    if (g == 0) {
      const int row = rowbase + c;
      if (row < NW) out[(size_t)b * NW + row] = a[0] * AMPF;
    }
  }
}

extern "C" void kernel_launch(void* const* d_in, const int* in_sizes, int n_in,
                              void* d_out, int out_size, void* d_ws, size_t ws_size,
                              hipStream_t stream) {
  const float* x  = (const float*)d_in[0];
  const float* cv = (const float*)d_in[1];
  const float* W1 = (const float*)d_in[2];
  const float* b1 = (const float*)d_in[3];
  const float* W2 = (const float*)d_in[4];
  const float* b2 = (const float*)d_in[5];
  const float* W3 = (const float*)d_in[6];
  const float* b3 = (const float*)d_in[7];
  const float* W4 = (const float*)d_in[8];
  const float* b4 = (const float*)d_in[9];
  const float* W5 = (const float*)d_in[10];
  const float* b5 = (const float*)d_in[11];
  const float* W6 = (const float*)d_in[12];
  const float* b6 = (const float*)d_in[13];
  float* out = (float*)d_out;
  uint4* frags = (uint4*)d_ws;   // 81 * 64 * 16 B = 82,944 B

  hipLaunchKernelGGL(dnpu_pack, dim3(21), dim3(256), 0, stream,
                     W1, b1, W2, b2, W3, b3, W4, b4, W5, b5, W6, b6, frags);
  // 8192 windows: 64 blocks x (4 waves * 32 windows)
  hipLaunchKernelGGL(dnpu_mfma, dim3(64, NB), dim3(256), 0, stream,
                     x, cv, frags, out);
}